// Round 3
// baseline (360.283 us; speedup 1.0000x reference)
//
#include <hip/hip_runtime.h>
#include <hip/hip_bf16.h>

#define BB 512
#define VV 6890
#define NJ 24
#define NBETA 10
#define NP 207          // (24-1)*9
#define N3 (VV*3)       // 20670
#define TBAT 16         // batch tile in k_posed: 288 FMA per 9-load chunk covers L2 latency
#define NCH 16          // v-chunks in k_jreg
#define CHV ((VV + NCH - 1) / NCH)   // 431
#define VB 4            // batch tile in k_verts

// d_out element offsets (fp32), concatenated in return order:
// verts (B,V,3), posed_joints (B,J,3), A (B,J,4,4), transforms (B,J,4,4), v_posed (B,V,3)
#define OFF_VERTS 0
#define OFF_PJ   (BB*VV*3)
#define OFF_A    (OFF_PJ + BB*NJ*3)
#define OFF_TF   (OFF_A + BB*NJ*16)
#define OFF_VP   (OFF_TF + BB*NJ*16)

// ws layout (fp32 elements) — total ~1.26 MB
#define WS_JP   0                        // NCH*24*33 partials of [JT[3]|JS[30]]
#define WS_PF   (WS_JP + NCH*NJ*33)      // B*207 pose_feature
#define WS_A    (WS_PF + BB*NP)          // B*24*16 fp32 A

// SMPL parents are a compile-time constant in the reference — hardcoded.
__constant__ int c_par[NJ] = {-1, 0, 0, 0, 1, 2, 3, 4, 5, 6, 7, 8,
                              9, 9, 9, 12, 13, 14, 16, 17, 18, 19, 20, 21};

// ------------------------------------------------- K1: partial JT/JS sums
// grid = (24, NCH); block (j, chunk) accumulates 33 dots over its v-range.
// jr read once per block; vt/sd read CONTIGUOUSLY per vertex (no strided columns).
__global__ __launch_bounds__(256) void k_jreg(const float* __restrict__ jr,
                                              const float* __restrict__ vt,
                                              const float* __restrict__ sd,
                                              float* __restrict__ ws_jp) {
    int j = blockIdx.x, ch = blockIdx.y;
    int t = threadIdx.x;
    int v0 = ch * CHV;
    int vend = (v0 + CHV < VV) ? (v0 + CHV) : VV;

    float acc[33];
#pragma unroll
    for (int i = 0; i < 33; i++) acc[i] = 0.f;

    for (int v = v0 + t; v < vend; v += 256) {
        float a = jr[(size_t)j * VV + v];
        acc[0] += a * vt[v * 3 + 0];
        acc[1] += a * vt[v * 3 + 1];
        acc[2] += a * vt[v * 3 + 2];
        const float2* sp = (const float2*)&sd[(size_t)v * 30];   // 8B-aligned
#pragma unroll
        for (int i = 0; i < 15; i++) {
            float2 s = sp[i];
            acc[3 + 2 * i] += a * s.x;
            acc[4 + 2 * i] += a * s.y;
        }
    }

    __shared__ float red[33][256];
#pragma unroll
    for (int i = 0; i < 33; i++) red[i][t] = acc[i];
    __syncthreads();
    for (int s = 128; s > 0; s >>= 1) {
        if (t < s) {
#pragma unroll
            for (int i = 0; i < 33; i++) red[i][t] += red[i][t + s];
        }
        __syncthreads();
    }
    if (t < 33) ws_jp[(size_t)(ch * NJ + j) * 33 + t] = red[t][0];
}

// ------------------------------- K2: Jloc, Rodrigues, chain, A/transforms/joints
__global__ __launch_bounds__(64) void k_chain(
        const float* __restrict__ betas,
        const float* __restrict__ pose,
        const float* __restrict__ ws_jp,
        float* __restrict__ ws_pf,
        float* __restrict__ ws_A,
        float* __restrict__ out) {
    int b = blockIdx.x;
    int t = threadIdx.x;
    __shared__ float Jl[NJ][3];
    __shared__ float tm[NJ][16];
    __shared__ float ch[NJ][16];
    float R[9];

    if (t < NJ) {
        int j = t;
        // sum the NCH partials for this joint's 33 values
        float s[33];
#pragma unroll
        for (int i = 0; i < 33; i++) s[i] = 0.f;
        for (int c = 0; c < NCH; c++) {
            const float* pp = ws_jp + (size_t)(c * NJ + j) * 33;
#pragma unroll
            for (int i = 0; i < 33; i++) s[i] += pp[i];
        }
        float bb[NBETA];
#pragma unroll
        for (int l = 0; l < NBETA; l++) bb[l] = betas[b * NBETA + l];
#pragma unroll
        for (int k = 0; k < 3; k++) {
            float acc = s[k];
#pragma unroll
            for (int l = 0; l < NBETA; l++) acc += bb[l] * s[3 + k * NBETA + l];
            Jl[j][k] = acc;
        }
        // Rodrigues, matching reference: angle = ||aa + 1e-8||, rd = aa/angle
        float ax = pose[b * NJ * 3 + j * 3 + 0];
        float ay = pose[b * NJ * 3 + j * 3 + 1];
        float az = pose[b * NJ * 3 + j * 3 + 2];
        float e0 = ax + 1e-8f, e1 = ay + 1e-8f, e2 = az + 1e-8f;
        float ang = sqrtf(e0 * e0 + e1 * e1 + e2 * e2);
        float inv = 1.f / ang;
        float rx = ax * inv, ry = ay * inv, rz = az * inv;
        float sn = sinf(ang), cs = cosf(ang);
        float Km[9] = {0.f, -rz, ry, rz, 0.f, -rx, -ry, rx, 0.f};
#pragma unroll
        for (int r = 0; r < 3; r++)
#pragma unroll
            for (int c = 0; c < 3; c++) {
                float kk = Km[3 * r + 0] * Km[0 + c] + Km[3 * r + 1] * Km[3 + c] +
                           Km[3 * r + 2] * Km[6 + c];
                R[3 * r + c] = ((r == c) ? 1.f : 0.f) + sn * Km[3 * r + c] + (1.f - cs) * kk;
            }
        if (j >= 1) {
#pragma unroll
            for (int e = 0; e < 9; e++) {
                int r = e / 3, c = e % 3;
                ws_pf[b * NP + (j - 1) * 9 + e] = R[e] - ((r == c) ? 1.f : 0.f);
            }
        }
    }
    __syncthreads();
    if (t < NJ) {
        int j = t;
        int p = c_par[j];
        int ps = (p < 0) ? 0 : p;
#pragma unroll
        for (int r = 0; r < 3; r++) {
            tm[j][r * 4 + 0] = R[3 * r + 0];
            tm[j][r * 4 + 1] = R[3 * r + 1];
            tm[j][r * 4 + 2] = R[3 * r + 2];
            tm[j][r * 4 + 3] = (j == 0) ? Jl[j][r] : (Jl[j][r] - Jl[ps][r]);
        }
        tm[j][12] = 0.f; tm[j][13] = 0.f; tm[j][14] = 0.f; tm[j][15] = 1.f;
    }
    __syncthreads();
    if (t < 16) ch[0][t] = tm[0][t];
    __syncthreads();
    for (int i = 1; i < NJ; i++) {
        if (t < 16) {
            int r = t >> 2, c = t & 3;
            int p = c_par[i];
            ch[i][t] = ch[p][4 * r + 0] * tm[i][0 + c] + ch[p][4 * r + 1] * tm[i][4 + c] +
                       ch[p][4 * r + 2] * tm[i][8 + c] + ch[p][4 * r + 3] * tm[i][12 + c];
        }
        __syncthreads();
    }
    if (t < NJ) {
        int j = t;
        float ib[4];
#pragma unroll
        for (int p = 0; p < 4; p++)
            ib[p] = ch[j][4 * p + 0] * Jl[j][0] + ch[j][4 * p + 1] * Jl[j][1] +
                    ch[j][4 * p + 2] * Jl[j][2];
#pragma unroll
        for (int e = 0; e < 16; e++) {
            int r = e >> 2, c = e & 3;
            float tr = ch[j][e];
            float Ae = tr - ((c == 3) ? ib[r] : 0.f);
            out[OFF_TF + (size_t)(b * NJ + j) * 16 + e] = tr;
            out[OFF_A + (size_t)(b * NJ + j) * 16 + e] = Ae;
            ws_A[(size_t)(b * NJ + j) * 16 + e] = Ae;
        }
#pragma unroll
        for (int k = 0; k < 3; k++)
            out[OFF_PJ + (size_t)(b * NJ + j) * 3 + k] = ch[j][4 * k + 3];
    }
}

// ----------- K3 helpers: double-buffered pd chunks
__device__ __forceinline__ void load9(const float* __restrict__ pdp, int c0,
                                      float* b0, float* b1) {
#pragma unroll
    for (int pc = 0; pc < 9; pc++) {
        float2 v = *(const float2*)&pdp[(size_t)(c0 + pc) * N3];
        b0[pc] = v.x; b1[pc] = v.y;
    }
}
__device__ __forceinline__ void comp9(const float* __restrict__ ws_pf, int b0, int c0,
                                      const float* pv0, const float* pv1,
                                      float* acc0, float* acc1) {
#pragma unroll
    for (int bi = 0; bi < TBAT; bi++) {
        const float* __restrict__ pfr = &ws_pf[(size_t)(b0 + bi) * NP + c0];  // uniform -> s_load
#pragma unroll
        for (int pc = 0; pc < 9; pc++) {
            float w = pfr[pc];
            acc0[bi] += w * pv0[pc];
            acc1[bi] += w * pv1[pc];
        }
    }
}

// ----------- K3: v_posed = v_template + sd@betas + pf@posedirs
// XCD-swizzled 1D grid: all same-x blocks land on ONE XCD so the 424KB pd
// slice stays L2-resident (verified: FETCH 119MB -> 16.5MB).
// TBAT=16: 288 FMA (576 cyc) per 9-load chunk.
// sched_barrier(0) after each load group: WITHOUT it the compiler sinks the
// loads to first use (r2 showed VGPR=36 < the 52 the dbuf needs -> pipeline
// was destroyed, full latency exposed on every load, VALUBusy stuck at 40%).
__global__ __launch_bounds__(256, 4) void k_posed(
        const float* __restrict__ vt,
        const float* __restrict__ sd,
        const float* __restrict__ betas,
        const float* __restrict__ pd,
        const float* __restrict__ ws_pf,
        float* __restrict__ out) {
    int id = blockIdx.x;
    int xcd = id & 7, li = id >> 3;
    int nx = (xcd == 0) ? 6 : 5;                 // x-slices owned by this XCD (41 = 6+7*5)
    if (li >= nx * (BB / TBAT)) return;
    int x = xcd + 8 * (li % nx);
    int b0 = (li / nx) * TBAT;
    int n0 = (x * 256 + threadIdx.x) * 2;
    if (n0 >= N3) return;

    float acc0[TBAT], acc1[TBAT];
#pragma unroll
    for (int bi = 0; bi < TBAT; bi++) { acc0[bi] = 0.f; acc1[bi] = 0.f; }

    float pA0[9], pA1[9], pB0[9], pB1[9];
    const float* __restrict__ pdp = pd + n0;

    // 23 chunks of 9: software-pipelined, double-buffered, schedule pinned.
    load9(pdp, 0, pA0, pA1);
#pragma unroll 1
    for (int c = 0; c < 11; c++) {
        int c0 = c * 18;
        load9(pdp, c0 + 9, pB0, pB1);            // issue next-chunk loads
        __builtin_amdgcn_sched_barrier(0);       // pin: loads stay above compute
        comp9(ws_pf, b0, c0, pA0, pA1, acc0, acc1);
        load9(pdp, c0 + 18, pA0, pA1);
        __builtin_amdgcn_sched_barrier(0);
        comp9(ws_pf, b0, c0 + 9, pB0, pB1, acc0, acc1);
    }
    comp9(ws_pf, b0, 198, pA0, pA1, acc0, acc1);

    float base0 = vt[n0], base1 = vt[n0 + 1];
    float sdv0[NBETA], sdv1[NBETA];
#pragma unroll
    for (int l = 0; l < NBETA; l++) {
        sdv0[l] = sd[(size_t)n0 * NBETA + l];
        sdv1[l] = sd[(size_t)(n0 + 1) * NBETA + l];
    }
#pragma unroll
    for (int bi = 0; bi < TBAT; bi++) {
        const float* __restrict__ br = &betas[(size_t)(b0 + bi) * NBETA];  // uniform
        float s0 = base0 + acc0[bi], s1 = base1 + acc1[bi];
#pragma unroll
        for (int l = 0; l < NBETA; l++) {
            float bl = br[l];
            s0 += bl * sdv0[l];
            s1 += bl * sdv1[l];
        }
        float2 o; o.x = s0; o.y = s1;
        *(float2*)&out[OFF_VP + (size_t)(b0 + bi) * N3 + n0] = o;
    }
}

// --------------------------------------------- K4: T = lw@A ; verts = T.vposed
// Batch-tiled x4: lw (24 regs) amortized over VB batches; A rows uniform -> s_load.
__global__ __launch_bounds__(256, 4) void k_verts(const float* __restrict__ lw,
                                                  const float* __restrict__ ws_A,
                                                  float* __restrict__ out) {
    int bq = blockIdx.y;                         // 0..BB/VB-1
    int v = blockIdx.x * 256 + threadIdx.x;
    if (v >= VV) return;

    float wv[NJ];
#pragma unroll
    for (int j0 = 0; j0 < NJ; j0 += 4) {
        const float4 w4 = *(const float4*)&lw[(size_t)v * NJ + j0];
        wv[j0 + 0] = w4.x; wv[j0 + 1] = w4.y; wv[j0 + 2] = w4.z; wv[j0 + 3] = w4.w;
    }

#pragma unroll
    for (int bb = 0; bb < VB; bb++) {
        int b = bq * VB + bb;
        const float* __restrict__ Ab = ws_A + (size_t)b * NJ * 16;
        float T[12];
#pragma unroll
        for (int e = 0; e < 12; e++) T[e] = 0.f;
#pragma unroll
        for (int j = 0; j < NJ; j++) {
            const float* __restrict__ Aj = Ab + j * 16;   // uniform -> s_load rows
            float wj = wv[j];
#pragma unroll
            for (int e = 0; e < 12; e++) T[e] += wj * Aj[e];
        }
        size_t base = (size_t)(b * VV + v) * 3;
        float xx = out[OFF_VP + base + 0];
        float yy = out[OFF_VP + base + 1];
        float zz = out[OFF_VP + base + 2];
#pragma unroll
        for (int p = 0; p < 3; p++) {
            out[OFF_VERTS + base + p] =
                T[4 * p + 0] * xx + T[4 * p + 1] * yy + T[4 * p + 2] * zz + T[4 * p + 3];
        }
    }
}

extern "C" void kernel_launch(void* const* d_in, const int* in_sizes, int n_in,
                              void* d_out, int out_size, void* d_ws, size_t ws_size,
                              hipStream_t stream) {
    const float* betas = (const float*)d_in[0];
    const float* pose  = (const float*)d_in[1];
    const float* vt    = (const float*)d_in[2];
    const float* sd    = (const float*)d_in[3];
    const float* pd    = (const float*)d_in[4];
    const float* jr    = (const float*)d_in[5];
    const float* lw    = (const float*)d_in[6];
    float* out = (float*)d_out;
    float* ws = (float*)d_ws;

    k_jreg<<<dim3(NJ, NCH), 256, 0, stream>>>(jr, vt, sd, ws + WS_JP);
    k_chain<<<BB, 64, 0, stream>>>(betas, pose, ws + WS_JP, ws + WS_PF,
                                   ws + WS_A, out);
    // 8 XCDs x max 6 x-slices x 32 batch-groups = 1536 (224 exit immediately)
    k_posed<<<8 * 6 * (BB / TBAT), 256, 0, stream>>>(
        vt, sd, betas, pd, ws + WS_PF, out);
    k_verts<<<dim3((VV + 255) / 256, BB / VB), 256, 0, stream>>>(lw, ws + WS_A, out);
}

// Round 5
// 250.125 us; speedup vs baseline: 1.4404x; 1.4404x over previous
//
#include <hip/hip_runtime.h>
#include <hip/hip_bf16.h>

#define BB 512
#define VV 6890
#define NJ 24
#define NBETA 10
#define NP 207          // (24-1)*9
#define N3 (VV*3)       // 20670
#define TBAT 16         // batch tile in k_fused: 432 FMA per 9-load chunk
#define NCH 16          // v-chunks in k_jreg
#define CHV ((VV + NCH - 1) / NCH)   // 431

// d_out element offsets (fp32), concatenated in return order:
// verts (B,V,3), posed_joints (B,J,3), A (B,J,4,4), transforms (B,J,4,4), v_posed (B,V,3)
#define OFF_VERTS 0
#define OFF_PJ   (BB*VV*3)
#define OFF_A    (OFF_PJ + BB*NJ*3)
#define OFF_TF   (OFF_A + BB*NJ*16)
#define OFF_VP   (OFF_TF + BB*NJ*16)

// ws layout (fp32 elements)
#define WS_JP   0                        // NCH*24*33 partials of [JT[3]|JS[30]]
#define WS_PF   (WS_JP + NCH*NJ*33)      // B*207 pose_feature
#define WS_A    (WS_PF + BB*NP)          // B*24*16 fp32 A

// SMPL parents are a compile-time constant in the reference — hardcoded.
__constant__ int c_par[NJ] = {-1, 0, 0, 0, 1, 2, 3, 4, 5, 6, 7, 8,
                              9, 9, 9, 12, 13, 14, 16, 17, 18, 19, 20, 21};

// ------------------------------------------------- K1: partial JT/JS sums
__global__ __launch_bounds__(256) void k_jreg(const float* __restrict__ jr,
                                              const float* __restrict__ vt,
                                              const float* __restrict__ sd,
                                              float* __restrict__ ws_jp) {
    int j = blockIdx.x, ch = blockIdx.y;
    int t = threadIdx.x;
    int v0 = ch * CHV;
    int vend = (v0 + CHV < VV) ? (v0 + CHV) : VV;

    float acc[33];
#pragma unroll
    for (int i = 0; i < 33; i++) acc[i] = 0.f;

    for (int v = v0 + t; v < vend; v += 256) {
        float a = jr[(size_t)j * VV + v];
        acc[0] += a * vt[v * 3 + 0];
        acc[1] += a * vt[v * 3 + 1];
        acc[2] += a * vt[v * 3 + 2];
        const float2* sp = (const float2*)&sd[(size_t)v * 30];   // 8B-aligned
#pragma unroll
        for (int i = 0; i < 15; i++) {
            float2 s = sp[i];
            acc[3 + 2 * i] += a * s.x;
            acc[4 + 2 * i] += a * s.y;
        }
    }

    __shared__ float red[33][256];
#pragma unroll
    for (int i = 0; i < 33; i++) red[i][t] = acc[i];
    __syncthreads();
    for (int s = 128; s > 0; s >>= 1) {
        if (t < s) {
#pragma unroll
            for (int i = 0; i < 33; i++) red[i][t] += red[i][t + s];
        }
        __syncthreads();
    }
    if (t < 33) ws_jp[(size_t)(ch * NJ + j) * 33 + t] = red[t][0];
}

// ------------------------------- K2: Jloc, Rodrigues, chain, A/transforms/joints
__global__ __launch_bounds__(64) void k_chain(
        const float* __restrict__ betas,
        const float* __restrict__ pose,
        const float* __restrict__ ws_jp,
        float* __restrict__ ws_pf,
        float* __restrict__ ws_A,
        float* __restrict__ out) {
    int b = blockIdx.x;
    int t = threadIdx.x;
    __shared__ float Jl[NJ][3];
    __shared__ float tm[NJ][16];
    __shared__ float ch[NJ][16];
    float R[9];

    if (t < NJ) {
        int j = t;
        float s[33];
#pragma unroll
        for (int i = 0; i < 33; i++) s[i] = 0.f;
        for (int c = 0; c < NCH; c++) {
            const float* pp = ws_jp + (size_t)(c * NJ + j) * 33;
#pragma unroll
            for (int i = 0; i < 33; i++) s[i] += pp[i];
        }
        float bb[NBETA];
#pragma unroll
        for (int l = 0; l < NBETA; l++) bb[l] = betas[b * NBETA + l];
#pragma unroll
        for (int k = 0; k < 3; k++) {
            float acc = s[k];
#pragma unroll
            for (int l = 0; l < NBETA; l++) acc += bb[l] * s[3 + k * NBETA + l];
            Jl[j][k] = acc;
        }
        // Rodrigues, matching reference: angle = ||aa + 1e-8||, rd = aa/angle
        float ax = pose[b * NJ * 3 + j * 3 + 0];
        float ay = pose[b * NJ * 3 + j * 3 + 1];
        float az = pose[b * NJ * 3 + j * 3 + 2];
        float e0 = ax + 1e-8f, e1 = ay + 1e-8f, e2 = az + 1e-8f;
        float ang = sqrtf(e0 * e0 + e1 * e1 + e2 * e2);
        float inv = 1.f / ang;
        float rx = ax * inv, ry = ay * inv, rz = az * inv;
        float sn = sinf(ang), cs = cosf(ang);
        float Km[9] = {0.f, -rz, ry, rz, 0.f, -rx, -ry, rx, 0.f};
#pragma unroll
        for (int r = 0; r < 3; r++)
#pragma unroll
            for (int c = 0; c < 3; c++) {
                float kk = Km[3 * r + 0] * Km[0 + c] + Km[3 * r + 1] * Km[3 + c] +
                           Km[3 * r + 2] * Km[6 + c];
                R[3 * r + c] = ((r == c) ? 1.f : 0.f) + sn * Km[3 * r + c] + (1.f - cs) * kk;
            }
        if (j >= 1) {
#pragma unroll
            for (int e = 0; e < 9; e++) {
                int r = e / 3, c = e % 3;
                ws_pf[b * NP + (j - 1) * 9 + e] = R[e] - ((r == c) ? 1.f : 0.f);
            }
        }
    }
    __syncthreads();
    if (t < NJ) {
        int j = t;
        int p = c_par[j];
        int ps = (p < 0) ? 0 : p;
#pragma unroll
        for (int r = 0; r < 3; r++) {
            tm[j][r * 4 + 0] = R[3 * r + 0];
            tm[j][r * 4 + 1] = R[3 * r + 1];
            tm[j][r * 4 + 2] = R[3 * r + 2];
            tm[j][r * 4 + 3] = (j == 0) ? Jl[j][r] : (Jl[j][r] - Jl[ps][r]);
        }
        tm[j][12] = 0.f; tm[j][13] = 0.f; tm[j][14] = 0.f; tm[j][15] = 1.f;
    }
    __syncthreads();
    if (t < 16) ch[0][t] = tm[0][t];
    __syncthreads();
    for (int i = 1; i < NJ; i++) {
        if (t < 16) {
            int r = t >> 2, c = t & 3;
            int p = c_par[i];
            ch[i][t] = ch[p][4 * r + 0] * tm[i][0 + c] + ch[p][4 * r + 1] * tm[i][4 + c] +
                       ch[p][4 * r + 2] * tm[i][8 + c] + ch[p][4 * r + 3] * tm[i][12 + c];
        }
        __syncthreads();
    }
    if (t < NJ) {
        int j = t;
        float ib[4];
#pragma unroll
        for (int p = 0; p < 4; p++)
            ib[p] = ch[j][4 * p + 0] * Jl[j][0] + ch[j][4 * p + 1] * Jl[j][1] +
                    ch[j][4 * p + 2] * Jl[j][2];
#pragma unroll
        for (int e = 0; e < 16; e++) {
            int r = e >> 2, c = e & 3;
            float tr = ch[j][e];
            float Ae = tr - ((c == 3) ? ib[r] : 0.f);
            out[OFF_TF + (size_t)(b * NJ + j) * 16 + e] = tr;
            out[OFF_A + (size_t)(b * NJ + j) * 16 + e] = Ae;
            ws_A[(size_t)(b * NJ + j) * 16 + e] = Ae;
        }
#pragma unroll
        for (int k = 0; k < 3; k++)
            out[OFF_PJ + (size_t)(b * NJ + j) * 3 + k] = ch[j][4 * k + 3];
    }
}

// ----------- K3 (FUSED): v_posed = vt + sd@betas + pf@posedirs ; verts = (lw@A)·vp
// One vertex (3 elems) per thread. XCD-swizzled: all same-x blocks on one XCD so
// the ~640KB pd slice stays L2-resident (r2-verified: FETCH 119MB -> 16.5MB) and
// pass-2's vp re-read hits the block's own just-written L2 lines.
// Single-buffer + ONE sched_barrier per chunk (loads above compute). NO dbuf
// across iterations — r3 showed dbuf+full-pin forces AGPR spills (VGPR=52 < live
// set 68 -> accvgpr copies -> VALU time x4).
__global__ __launch_bounds__(256, 4) void k_fused(
        const float* __restrict__ vt,
        const float* __restrict__ sd,
        const float* __restrict__ betas,
        const float* __restrict__ pd,
        const float* __restrict__ ws_pf,
        const float* __restrict__ ws_A,
        const float* __restrict__ lw,
        float* __restrict__ out) {
    int id = blockIdx.x;
    int xcd = id & 7, li = id >> 3;
    int nx = (xcd < 3) ? 4 : 3;                  // 27 x-slices = 3*4 + 5*3
    if (li >= nx * (BB / TBAT)) return;
    int x = xcd + 8 * (li % nx);
    int b0 = (li / nx) * TBAT;
    int v = x * 256 + threadIdx.x;               // vertex index
    if (v >= VV) return;
    int n0 = v * 3;

    float acc0[TBAT], acc1[TBAT], acc2[TBAT];
#pragma unroll
    for (int bi = 0; bi < TBAT; bi++) { acc0[bi] = 0.f; acc1[bi] = 0.f; acc2[bi] = 0.f; }

    const float* __restrict__ pdp = pd + n0;

    // ---- main loop: 23 chunks of 9 pose-feature rows
#pragma unroll 1
    for (int c0 = 0; c0 < NP; c0 += 9) {
        float p0[9], p1[9], p2[9];
#pragma unroll
        for (int pc = 0; pc < 9; pc++) {
            const float* rp = pdp + (size_t)(c0 + pc) * N3;
            p0[pc] = rp[0]; p1[pc] = rp[1]; p2[pc] = rp[2];   // dwordx3, 768B/wave
        }
        __builtin_amdgcn_sched_barrier(0);       // loads stay grouped above compute
#pragma unroll
        for (int bi = 0; bi < TBAT; bi++) {
            const float* __restrict__ pfr = &ws_pf[(size_t)(b0 + bi) * NP + c0];  // uniform -> s_load
#pragma unroll
            for (int pc = 0; pc < 9; pc++) {
                float w = pfr[pc];
                acc0[bi] += w * p0[pc];
                acc1[bi] += w * p1[pc];
                acc2[bi] += w * p2[pc];
            }
        }
    }

    // ---- pass 1: vp = vt + sd@betas + acc ; store (fully unrolled: acc stays in regs)
    float vt0 = vt[n0], vt1 = vt[n0 + 1], vt2 = vt[n0 + 2];
    float sdv[3][NBETA];
#pragma unroll
    for (int k = 0; k < 3; k++)
#pragma unroll
        for (int l = 0; l < NBETA; l++)
            sdv[k][l] = sd[(size_t)v * 30 + k * NBETA + l];   // contiguous -> merged loads
#pragma unroll
    for (int bi = 0; bi < TBAT; bi++) {
        const float* __restrict__ br = &betas[(size_t)(b0 + bi) * NBETA];  // uniform
        float s0 = vt0 + acc0[bi], s1 = vt1 + acc1[bi], s2 = vt2 + acc2[bi];
#pragma unroll
        for (int l = 0; l < NBETA; l++) {
            float bl = br[l];
            s0 += bl * sdv[0][l];
            s1 += bl * sdv[1][l];
            s2 += bl * sdv[2][l];
        }
        float* op = &out[OFF_VP + (size_t)(b0 + bi) * N3 + n0];
        op[0] = s0; op[1] = s1; op[2] = s2;
    }

    // ---- pass 2: verts = (lw@A)[:3]·vph. bi-loop NOT unrolled (rule #20: runtime
    // index into acc would force scratch) -> re-read vp from our own L2 lines.
    float wv[NJ];
#pragma unroll
    for (int j0 = 0; j0 < NJ; j0 += 4) {
        const float4 w4 = *(const float4*)&lw[(size_t)v * NJ + j0];  // v*96B: 16B-aligned
        wv[j0 + 0] = w4.x; wv[j0 + 1] = w4.y; wv[j0 + 2] = w4.z; wv[j0 + 3] = w4.w;
    }
#pragma unroll 1
    for (int bi = 0; bi < TBAT; bi++) {
        int b = b0 + bi;
        const float* __restrict__ Ab = ws_A + (size_t)b * NJ * 16;
        float T[12];
#pragma unroll
        for (int e = 0; e < 12; e++) T[e] = 0.f;
#pragma unroll
        for (int j = 0; j < NJ; j++) {
            const float* __restrict__ Aj = Ab + j * 16;   // uniform -> s_load rows
            float wj = wv[j];
#pragma unroll
            for (int e = 0; e < 12; e++) T[e] += wj * Aj[e];
        }
        const float* ip = &out[OFF_VP + (size_t)b * N3 + n0];   // L2-hot (we wrote it)
        float xx = ip[0], yy = ip[1], zz = ip[2];
        float* op = &out[OFF_VERTS + (size_t)b * N3 + n0];
#pragma unroll
        for (int p = 0; p < 3; p++)
            op[p] = T[4 * p + 0] * xx + T[4 * p + 1] * yy + T[4 * p + 2] * zz + T[4 * p + 3];
    }
}

extern "C" void kernel_launch(void* const* d_in, const int* in_sizes, int n_in,
                              void* d_out, int out_size, void* d_ws, size_t ws_size,
                              hipStream_t stream) {
    const float* betas = (const float*)d_in[0];
    const float* pose  = (const float*)d_in[1];
    const float* vt    = (const float*)d_in[2];
    const float* sd    = (const float*)d_in[3];
    const float* pd    = (const float*)d_in[4];
    const float* jr    = (const float*)d_in[5];
    const float* lw    = (const float*)d_in[6];
    float* out = (float*)d_out;
    float* ws = (float*)d_ws;

    k_jreg<<<dim3(NJ, NCH), 256, 0, stream>>>(jr, vt, sd, ws + WS_JP);
    k_chain<<<BB, 64, 0, stream>>>(betas, pose, ws + WS_JP, ws + WS_PF,
                                   ws + WS_A, out);
    // 8 XCDs x max 4 x-slices x 32 batch-groups = 1024 launched, 864 live
    k_fused<<<8 * 4 * (BB / TBAT), 256, 0, stream>>>(
        vt, sd, betas, pd, ws + WS_PF, ws + WS_A, lw, out);
}